// Round 5
// baseline (143.273 us; speedup 1.0000x reference)
//
#include <hip/hip_runtime.h>
#include <math.h>

// SemanticDriftCoeff — band+prefix, v11:
// (a) k_gemm3: 64x128 tile kept (1056 = 8*132 blocks) but 2 waves x (64x64)
//     each: 8 ds_read_b128 per 16 MFMA (0.5 KB/MFMA vs v10's 0.75); 24.3 KB
//     LDS -> 6 blocks/CU (12 waves, better phase diversity, 2-wave barriers).
//     K-slice order 0,32,...,864 per output identical to v6-v10 -> bit-identical.
// (b) scan re-segmented 128x32 -> 256x16: k_segc chains 32->16 iters and
//     2->4 waves/CU; k_segb does a 4-value/lane Kogge-Stone over 256 segs.
// ws: invnorm[T], dmaxu[T], gn2[T], dist2[T], invLb[T], Sseg[256*D],
// Eseg[256*D], P[T*D] f32; hb[T*D], hbTp[D*(T+64)], gb[T*D], wband[T*64] bf16.

#define T_ 4096
#define D_ 896
#define TP (T_ + 64)   // padded hbTp row stride (ushorts)

typedef float f32x4 __attribute__((ext_vector_type(4)));
typedef unsigned short u16x8 __attribute__((ext_vector_type(8)));
typedef __bf16 bf16x8 __attribute__((ext_vector_type(8)));

union V16 { uint4 u; u16x8 v; };

__device__ __forceinline__ u16x8 ld16(const unsigned short* p) {
  V16 x; x.u = *(const uint4*)p; return x.v;
}
__device__ __forceinline__ void st16(unsigned short* p, u16x8 v) {
  V16 x; x.v = v; *(uint4*)p = x.u;
}
__device__ __forceinline__ unsigned short f2bf(float f) {  // RNE float->bf16 bits
  unsigned int u = __float_as_uint(f);
  u += 0x7FFFu + ((u >> 16) & 1u);
  return (unsigned short)(u >> 16);
}
__device__ __forceinline__ float bf2f(unsigned short b) {
  return __uint_as_float(((unsigned int)b) << 16);
}
__device__ __forceinline__ float4 bf4f(uint2 u) {
  return make_float4(bf2f((unsigned short)(u.x & 0xffff)),
                     bf2f((unsigned short)(u.x >> 16)),
                     bf2f((unsigned short)(u.y & 0xffff)),
                     bf2f((unsigned short)(u.y >> 16)));
}
__device__ __forceinline__ f32x4 mfma16(u16x8 a, u16x8 b, f32x4 c) {
  return __builtin_amdgcn_mfma_f32_16x16x32_bf16(
      __builtin_bit_cast(bf16x8, a), __builtin_bit_cast(bf16x8, b), c, 0, 0, 0);
}

typedef __attribute__((address_space(1))) const void glob_cv;
typedef __attribute__((address_space(3))) void lds_v;
__device__ __forceinline__ void gload16(const void* g, void* l) {
  __builtin_amdgcn_global_load_lds((glob_cv*)g, (lds_v*)l, 16, 0, 0);
}

// 256-thread tile stage with XOR group swizzle on the GLOBAL source
// (LDS dest linear, m173 pattern).
__device__ __forceinline__ void stage32(const unsigned short* __restrict__ g0,
                                        int stride, unsigned short* lds0, int tid) {
  #pragma unroll
  for (int it = 0; it < 2; ++it) {
    const int e = it * 256 + tid;            // e in [0,512)
    const int row = e >> 3, pg = e & 7;
    const int gg = pg ^ (row & 7);
    gload16(g0 + (size_t)row * stride + gg * 8, lds0 + e * 8);
  }
}

// 128-thread variant: ITERS*128 ushort8 groups (ITERS=4 -> 64 rows of 64).
template <int ITERS>
__device__ __forceinline__ void stage128t(const unsigned short* __restrict__ g0,
                                          int stride, unsigned short* lds0, int tid) {
  #pragma unroll
  for (int it = 0; it < ITERS; ++it) {
    const int e = it * 128 + tid;
    const int row = e >> 3, pg = e & 7;
    const int gg = pg ^ (row & 7);
    gload16(g0 + (size_t)row * stride + gg * 8, lds0 + e * 8);
  }
}

// Decode block id -> (ti: 64-row tile, sj: 128-col tile), causal.
// Row-pair p contributes 2(p+1) blocks; cumulative before p is p(p+1).
__device__ __forceinline__ void tri2_decode(int b, int& ti, int& sj) {
  int p = (int)((sqrtf(4.0f * (float)b + 1.0f) - 1.0f) * 0.5f);
  while ((p + 1) * (p + 2) <= b) ++p;
  while (p * (p + 1) > b) --p;
  const int r = b - p * (p + 1);
  if (r >= p + 1) { ti = 2 * p + 1; sj = r - (p + 1); }
  else            { ti = 2 * p;     sj = r; }
}

// ---------- prep: invnorm + bf16 normalized rows ----------
__global__ __launch_bounds__(256) void k_prep(const float* __restrict__ x,
    float* __restrict__ invnorm, unsigned short* __restrict__ hb) {
  const int t = (int)blockIdx.x, tid = (int)threadIdx.x;
  const int c = tid * 4;
  float4 v = make_float4(0.f, 0.f, 0.f, 0.f);
  float s = 0.f;
  if (c < D_) {
    v = *(const float4*)(x + (size_t)t * D_ + c);
    s = v.x * v.x + v.y * v.y + v.z * v.z + v.w * v.w;
  }
  __shared__ float sb[4];
  __shared__ float sinv;
  #pragma unroll
  for (int off = 32; off > 0; off >>= 1) s += __shfl_down(s, off, 64);
  if ((tid & 63) == 0) sb[tid >> 6] = s;
  __syncthreads();
  if (tid == 0) {
    const float tot = sb[0] + sb[1] + sb[2] + sb[3];
    const float iv = 1.0f / fmaxf(sqrtf(tot), 1e-12f);
    invnorm[t] = iv; sinv = iv;
  }
  __syncthreads();
  if (c < D_) {
    const float iv = sinv;
    *(ushort4*)(hb + (size_t)t * D_ + c) = make_ushort4(
        f2bf(v.x * iv), f2bf(v.y * iv), f2bf(v.z * iv), f2bf(v.w * iv));
  }
}

// ---------- 32x32 transpose hb -> hbTp (data at col offset 32, front zeroed) ----------
__global__ __launch_bounds__(256) void k_transp(const unsigned short* __restrict__ hb,
                                                unsigned short* __restrict__ hbTp) {
  __shared__ unsigned short Ts[32][36];
  const int t0 = (int)blockIdx.x * 32, d0 = (int)blockIdx.y * 32;
  const int r = (int)threadIdx.x >> 3, c = ((int)threadIdx.x & 7) * 4;
  const ushort4 v = *(const ushort4*)(hb + (size_t)(t0 + r) * D_ + d0 + c);
  Ts[r][c] = v.x; Ts[r][c + 1] = v.y; Ts[r][c + 2] = v.z; Ts[r][c + 3] = v.w;
  __syncthreads();
  const ushort4 o = make_ushort4(Ts[c][r], Ts[c + 1][r], Ts[c + 2][r], Ts[c + 3][r]);
  *(ushort4*)(hbTp + (size_t)(d0 + r) * TP + 32 + t0 + c) = o;
  if (blockIdx.x == 0)   // zero the 32 leading pad cols for these 32 d rows
    *(ushort4*)(hbTp + (size_t)(d0 + r) * TP + c) = make_ushort4(0, 0, 0, 0);
}

// ---------- scan: 256 segments x 16 rows ----------
__global__ __launch_bounds__(256) void k_sega(const unsigned short* __restrict__ hb,
                                              float* __restrict__ Sseg) {
  const int seg = (int)blockIdx.x, tid = (int)threadIdx.x;
  const int wv = tid >> 6, lane = tid & 63;
  __shared__ float4 part[4][56];
  const int c = (int)blockIdx.y * 224 + lane * 4;
  float4 acc = make_float4(0.f, 0.f, 0.f, 0.f);
  if (lane < 56) {
    #pragma unroll
    for (int r = 0; r < 4; ++r) {
      const int row = seg * 16 + wv * 4 + r;
      const float4 h = bf4f(*(const uint2*)(hb + (size_t)row * D_ + c));
      acc.x += h.x; acc.y += h.y; acc.z += h.z; acc.w += h.w;
    }
    part[wv][lane] = acc;
  }
  __syncthreads();
  if (wv == 0 && lane < 56) {
    const float4 a = part[0][lane], b = part[1][lane];
    const float4 d = part[2][lane], e = part[3][lane];
    *(float4*)(Sseg + (size_t)seg * D_ + c) = make_float4(
        a.x + b.x + d.x + e.x, a.y + b.y + d.y + e.y,
        a.z + b.z + d.z + e.z, a.w + b.w + d.w + e.w);
  }
}

// wave-scan of 256 segments (4x64 per lane) — one column per wave
__global__ __launch_bounds__(256) void k_segb(const float* __restrict__ Sseg,
                                              float* __restrict__ Eseg) {
  const int tid = (int)threadIdx.x;
  const int wv = tid >> 6, lane = tid & 63;
  const int c = (int)blockIdx.x * 4 + wv;     // column 0..895
  float v0 = Sseg[(size_t)lane * D_ + c];
  float v1 = Sseg[(size_t)(64 + lane) * D_ + c];
  float v2 = Sseg[(size_t)(128 + lane) * D_ + c];
  float v3 = Sseg[(size_t)(192 + lane) * D_ + c];
  const float o0 = v0, o1 = v1, o2 = v2, o3 = v3;
  #pragma unroll
  for (int off = 1; off < 64; off <<= 1) {
    const float n0 = __shfl_up(v0, off, 64);
    const float n1 = __shfl_up(v1, off, 64);
    const float n2 = __shfl_up(v2, off, 64);
    const float n3 = __shfl_up(v3, off, 64);
    if (lane >= off) { v0 += n0; v1 += n1; v2 += n2; v3 += n3; }
  }
  const float tot0 = __shfl(v0, 63, 64);
  const float tot1 = __shfl(v1, 63, 64);
  const float tot2 = __shfl(v2, 63, 64);
  Eseg[(size_t)lane * D_ + c] = v0 - o0;              // exclusive
  Eseg[(size_t)(64 + lane) * D_ + c] = v1 - o1 + tot0;
  Eseg[(size_t)(128 + lane) * D_ + c] = v2 - o2 + (tot0 + tot1);
  Eseg[(size_t)(192 + lane) * D_ + c] = v3 - o3 + (tot0 + tot1 + tot2);
}

__global__ __launch_bounds__(64) void k_segc(const unsigned short* __restrict__ hb,
    const float* __restrict__ Eseg, float* __restrict__ P) {
  const int seg = (int)blockIdx.x, tid = (int)threadIdx.x;
  if (tid >= 56) return;
  const int c = (int)blockIdx.y * 224 + tid * 4;
  float4 run = *(const float4*)(Eseg + (size_t)seg * D_ + c);
  for (int r = 0; r < 16; ++r) {
    const int row = seg * 16 + r;
    const float4 h = bf4f(*(const uint2*)(hb + (size_t)row * D_ + c));
    run.x += h.x; run.y += h.y; run.z += h.z; run.w += h.w;
    *(float4*)(P + (size_t)row * D_ + c) = run;      // inclusive P(row)
  }
}

// ---------- bandw: diagonal sims (deep-MLP loads) -> weights + invL ----------
__global__ __launch_bounds__(256) void k_bandw(const unsigned short* __restrict__ hb,
    unsigned short* __restrict__ wband, float* __restrict__ invLb) {
  const int t0 = (int)blockIdx.x * 16;
  const int tid = (int)threadIdx.x;
  const int wv = tid >> 6, lane = tid & 63;
  const int tcol = lane & 15, quad = lane >> 4;
  __shared__ float sims[16][52];
  if (wv < 3) {
    const int s_base = t0 - 32 + wv * 16;
    if (s_base + 15 >= 0) {
      const int srow = max(s_base + tcol, 0);   // clamped; guarded below
      f32x4 acc = {};
      const unsigned short* arow = hb + (size_t)srow * D_ + quad * 8;
      const unsigned short* brow = hb + (size_t)(t0 + tcol) * D_ + quad * 8;
      #pragma unroll 1
      for (int c4 = 0; c4 < 4; ++c4) {          // 7 load-pairs in flight per step
        u16x8 av[7], bv[7];
        #pragma unroll
        for (int i = 0; i < 7; ++i) {
          av[i] = ld16(arow + (c4 * 7 + i) * 32);
          bv[i] = ld16(brow + (c4 * 7 + i) * 32);
        }
        #pragma unroll
        for (int i = 0; i < 7; ++i) acc = mfma16(av[i], bv[i], acc);
      }
      #pragma unroll
      for (int r = 0; r < 4; ++r)       // C[m=s_local=quad*4+r][n=t_local=tcol]
        sims[tcol][wv * 16 + quad * 4 + r] = acc[r];
    }
  }
  __syncthreads();
  if (wv == 0) {
    u16x8 af0, af1;
    float lsum = 0.f;
    #pragma unroll
    for (int j = 0; j < 8; ++j) {
      {
        const int k = quad * 8 + j;                 // k in [0,32)
        const int dt = tcol + 32 - k;               // >= 1
        const int s = t0 - 32 + k;
        unsigned short wb = 0;
        if (dt < 32 && s >= 0)
          wb = f2bf(__expf(sims[tcol][k] * (__expf(-0.1f * (float)dt) * 0.033407657f)));
        af0[j] = wb;
        lsum += bf2f(wb);
      }
      {
        const int k = 32 + quad * 8 + j;            // k in [32,64)
        const int dt = tcol + 32 - k;               // <= 15
        unsigned short wb = 0;
        if (dt >= 0)                                // k <= tcol+32 <= 47
          wb = f2bf(__expf(sims[tcol][k] * (__expf(-0.1f * (float)dt) * 0.033407657f)));
        af1[j] = wb;
        lsum += bf2f(wb);
      }
    }
    lsum += __shfl_xor(lsum, 16, 64);
    lsum += __shfl_xor(lsum, 32, 64);
    st16(wband + (size_t)(t0 + tcol) * 64 + quad * 8, af0);
    st16(wband + (size_t)(t0 + tcol) * 64 + 32 + quad * 8, af1);
    if (lane < 16) {
      const int t = t0 + lane;
      invLb[t] = 1.0f / (lsum + ((t >= 32) ? (float)(t - 31) : 0.f));
    }
  }
}

// ---------- bandg: band GEMM (2048 blocks) + epilogue, no LDS ----------
__global__ __launch_bounds__(256) void k_bandg(const unsigned short* __restrict__ hbTp,
    const unsigned short* __restrict__ wband, const float* __restrict__ invLb,
    const float* __restrict__ P, const float* __restrict__ x,
    const float* __restrict__ invnorm, unsigned short* __restrict__ gb,
    float* __restrict__ gn2, float* __restrict__ dist2) {
  const int t0 = (int)blockIdx.x * 16;
  const int by = (int)blockIdx.y;             // 8 d-groups of 7 tiles
  const int tid = (int)threadIdx.x;
  const int wv = tid >> 6, lane = tid & 63;
  const int tcol = lane & 15, quad = lane >> 4;
  const u16x8 af0 = ld16(wband + (size_t)(t0 + tcol) * 64 + quad * 8);
  const u16x8 af1 = ld16(wband + (size_t)(t0 + tcol) * 64 + 32 + quad * 8);
  float invLr[4], inrr[4];
  #pragma unroll
  for (int r = 0; r < 4; ++r) {
    const int tt = t0 + quad * 4 + r;
    invLr[r] = invLb[tt];
    inrr[r]  = invnorm[tt];
  }
  float sgl[4] = {0.f, 0.f, 0.f, 0.f}, sdl[4] = {0.f, 0.f, 0.f, 0.f};
  for (int i = wv; i < 7; i += 4) {
    const int d = (by * 7 + i) * 16 + tcol;
    const unsigned short* brow = hbTp + (size_t)d * TP + t0 + quad * 8;
    const u16x8 b0 = ld16(brow);          // k in [0,32): zeros where s<0
    const u16x8 b1 = ld16(brow + 32);     // k in [32,64): tail x w=0 harmless
    f32x4 C = {};
    C = mfma16(af0, b0, C);
    C = mfma16(af1, b1, C);
    #pragma unroll
    for (int r = 0; r < 4; ++r) {     // C[m=quad*4+r -> t][n=tcol -> d]
      const int tt = t0 + quad * 4 + r;
      float gacc = C[r];
      if (tt >= 32) gacc += P[(size_t)(tt - 32) * D_ + d];
      const float g = gacc * invLr[r];
      gb[(size_t)tt * D_ + d] = f2bf(g);
      const float e = x[(size_t)tt * D_ + d] * inrr[r] - g;
      sgl[r] += g * g;
      sdl[r] += e * e;
    }
  }
  #pragma unroll
  for (int r = 0; r < 4; ++r) {
    float sg = sgl[r], sd = sdl[r];
    sg += __shfl_xor(sg, 1, 64); sg += __shfl_xor(sg, 2, 64);
    sg += __shfl_xor(sg, 4, 64); sg += __shfl_xor(sg, 8, 64);
    sd += __shfl_xor(sd, 1, 64); sd += __shfl_xor(sd, 2, 64);
    sd += __shfl_xor(sd, 4, 64); sd += __shfl_xor(sd, 8, 64);
    if (tcol == 0) {
      atomicAdd(&gn2[t0 + quad * 4 + r], sg);
      atomicAdd(&dist2[t0 + quad * 4 + r], sd);
    }
  }
}

// ---------- GEMM3: cross = g h^T, 64x128 causal tiles (1056 blocks); row-max ----------
// v11: 2 waves x (64 rows x 64 cols) each -> per ks: 8 ds_read_b128 feed
// 16 MFMA (0.5 KB/MFMA). 24.3 KB LDS -> 6 blocks/CU (12 waves/CU, 6
// independent blocks hide each other's stage latency; 2-wave barriers).
__global__ __launch_bounds__(128, 3) void k_gemm3(const unsigned short* __restrict__ gb,
    const unsigned short* __restrict__ hb, const float* __restrict__ gn2,
    unsigned int* __restrict__ dmaxu) {
  // Bijective XCD swizzle: 1056 = 8*132.
  const int bswz = ((int)blockIdx.x & 7) * 132 + ((int)blockIdx.x >> 3);
  int ti, sj;
  tri2_decode(bswz, ti, sj);
  const int t0 = ti * 64, s0 = sj * 128;
  __shared__ unsigned short As[64 * 64];    // 8 KB  (t rows)
  __shared__ unsigned short Bs[128 * 64];   // 16 KB (s rows)
  __shared__ unsigned int dmx[64];          // per-block row-max merge
  const int tid = (int)threadIdx.x;
  const int lane = tid & 63, wv = tid >> 6;       // wv in {0,1}
  const int tcol = lane & 15, quad = lane >> 4;
  if (tid < 64) dmx[tid] = 0u;
  f32x4 acc[4][4] = {};

  for (int kc = 0; kc < 14; ++kc) {
    __syncthreads();   // prev chunk's reads done before overwrite (also fences dmx init)
    stage128t<4>(gb + (size_t)t0 * D_ + kc * 64, D_, As, tid);
    stage128t<8>(hb + (size_t)s0 * D_ + kc * 64, D_, Bs, tid);
    __syncthreads();   // staged data visible
    #pragma unroll
    for (int ks = 0; ks < 2; ++ks) {
      const int go = ((ks * 4 + quad) ^ (tcol & 7)) * 8;
      u16x8 af[4], bf[4];
      #pragma unroll
      for (int mi = 0; mi < 4; ++mi)
        af[mi] = ld16(&As[(mi * 16 + tcol) * 64 + go]);
      #pragma unroll
      for (int ni = 0; ni < 4; ++ni)
        bf[ni] = ld16(&Bs[(wv * 64 + ni * 16 + tcol) * 64 + go]);
      #pragma unroll
      for (int mi = 0; mi < 4; ++mi)
        #pragma unroll
        for (int ni = 0; ni < 4; ++ni)
          acc[mi][ni] = mfma16(af[mi], bf[ni], acc[mi][ni]);
    }
  }

  // epilogue: m2[t] = max over this wave's 64-col strip, merge in LDS, then global
  #pragma unroll
  for (int mi = 0; mi < 4; ++mi) {
    #pragma unroll
    for (int r = 0; r < 4; ++r) {
      const int t = t0 + mi * 16 + quad * 4 + r;
      const float gn = gn2[t];
      float m2 = 0.f;
      #pragma unroll
      for (int ni = 0; ni < 4; ++ni) {
        const int s = s0 + wv * 64 + ni * 16 + tcol;
        if (t >= s)
          m2 = fmaxf(m2, fmaxf(1.0f - 2.0f * acc[mi][ni][r] + gn, 1e-24f));
      }
      m2 = fmaxf(m2, __shfl_xor(m2, 1, 64));
      m2 = fmaxf(m2, __shfl_xor(m2, 2, 64));
      m2 = fmaxf(m2, __shfl_xor(m2, 4, 64));
      m2 = fmaxf(m2, __shfl_xor(m2, 8, 64));
      if (tcol == 0 && m2 > 0.f)
        atomicMax(&dmx[mi * 16 + quad * 4 + r], __float_as_uint(m2));
    }
  }
  __syncthreads();
  if (tid < 64) {
    const unsigned int v = dmx[tid];
    if (v) atomicMax(&dmaxu[t0 + tid], v);
  }
}

__global__ __launch_bounds__(256) void k_final(const float* __restrict__ m_t,
    const float* __restrict__ c_t, const float* __restrict__ d_t,
    const float* __restrict__ mu, const float* __restrict__ dist2,
    const unsigned int* __restrict__ dmaxu, float* __restrict__ out) {
  const int t = (int)blockIdx.x * 256 + (int)threadIdx.x;
  if (t >= T_) return;
  float ratio;
  if (t == 0) {
    ratio = 0.f;  // ref: dist~1e-12, dist_max<1e-6 -> 1.0 => ratio ~0
  } else {
    float dmax = sqrtf(__uint_as_float(dmaxu[t]));
    if (dmax < 1e-6f) dmax = 1.0f;
    ratio = sqrtf(fmaxf(dist2[t], 1e-24f)) / (dmax + 1e-8f);
  }
  const float stab = 1.0f - 0.3f * c_t[t] + 0.2f * d_t[t];
  const float xi = 1.0f - mu[0] * m_t[t];
  out[t] = fminf(fmaxf(ratio * stab * xi, 0.f), 1.f);
}

extern "C" void kernel_launch(void* const* d_in, const int* in_sizes, int n_in,
                              void* d_out, int out_size, void* d_ws, size_t ws_size,
                              hipStream_t stream) {
  const float* x   = (const float*)d_in[0];
  const float* m_t = (const float*)d_in[1];
  const float* c_t = (const float*)d_in[2];
  const float* d_t = (const float*)d_in[3];
  const float* mu  = (const float*)d_in[4];
  float* out = (float*)d_out;

  float* ws = (float*)d_ws;
  float* invnorm = ws;                                          // [T]
  unsigned int* dmaxu = (unsigned int*)(ws + (size_t)T_);       // [T]
  float* gn2     = ws + 2 * (size_t)T_;                         // [T]
  float* dist2   = ws + 3 * (size_t)T_;                         // [T]
  float* invLb   = ws + 4 * (size_t)T_;                         // [T]
  float* Sseg    = ws + 5 * (size_t)T_;                         // [256*D]
  float* Eseg    = Sseg + 256 * (size_t)D_;                     // [256*D]
  float* P       = Eseg + 256 * (size_t)D_;                     // [T*D] fp32
  unsigned short* hb    = (unsigned short*)(P + (size_t)T_ * D_);  // [T*D]
  unsigned short* hbTp  = hb + (size_t)T_ * D_;                    // [D*(T+64)]
  unsigned short* gb    = hbTp + (size_t)D_ * TP;                  // [T*D]
  unsigned short* wband = gb + (size_t)T_ * D_;                    // [T*64]

  // zero dmaxu + gn2 + dist2 (contiguous 3T words)
  hipMemsetAsync(dmaxu, 0, 3 * (size_t)T_ * sizeof(unsigned int), stream);

  k_prep<<<T_, 256, 0, stream>>>(x, invnorm, hb);
  k_transp<<<dim3(T_ / 32, D_ / 32), 256, 0, stream>>>(hb, hbTp);
  k_sega<<<dim3(256, 4), 256, 0, stream>>>(hb, Sseg);
  k_segb<<<224, 256, 0, stream>>>(Sseg, Eseg);
  k_segc<<<dim3(256, 4), 64, 0, stream>>>(hb, Eseg, P);
  k_bandw<<<T_ / 16, 256, 0, stream>>>(hb, wband, invLb);
  k_bandg<<<dim3(T_ / 16, 8), 256, 0, stream>>>(hbTp, wband, invLb, P, x, invnorm,
                                                gb, gn2, dist2);
  k_gemm3<<<1056, 128, 0, stream>>>(gb, hb, gn2, dmaxu);
  k_final<<<(T_ + 255) / 256, 256, 0, stream>>>(m_t, c_t, d_t, mu, dist2, dmaxu, out);
}

// Round 6
// 142.405 us; speedup vs baseline: 1.0061x; 1.0061x over previous
//
#include <hip/hip_runtime.h>
#include <math.h>

// SemanticDriftCoeff — band+prefix, v12: fusion pass.
// (a) k_prep2 = prep + transp + sega fused (128 blocks x 32 rows, 57.6KB LDS
//     bf16 tile): invnorm + hb + hbTp + Sseg in one kernel.
// (b) P / k_segc eliminated: k_bandg recomputes P(t0-32+j) in-register from
//     Eseg[sg][d] + 16 sequential bf16 adds of hbTp[d][t0..t0+15] (same
//     left-assoc f32 order as old k_segc -> bit-identical).
// (c) k_gemm3 reverted to v10 config (best measured: 64x128 tile, 4 waves x
//     64x32, 1056 = 8*132 blocks, plain 2-barrier loop).
// Launches 10 -> 7.
// ws: invnorm[T], dmaxu[T], gn2[T], dist2[T], invLb[T], Sseg[256*D],
// Eseg[256*D], (P region unused); hb[T*D], hbTp[D*(T+64)], gb[T*D],
// wband[T*64] bf16.

#define T_ 4096
#define D_ 896
#define TP (T_ + 64)   // padded hbTp row stride (ushorts)
#define PSTR 900       // k_prep2 LDS row stride (ushorts), mult of 4, bank-spread

typedef float f32x4 __attribute__((ext_vector_type(4)));
typedef unsigned short u16x8 __attribute__((ext_vector_type(8)));
typedef __bf16 bf16x8 __attribute__((ext_vector_type(8)));

union V16 { uint4 u; u16x8 v; };

__device__ __forceinline__ u16x8 ld16(const unsigned short* p) {
  V16 x; x.u = *(const uint4*)p; return x.v;
}
__device__ __forceinline__ void st16(unsigned short* p, u16x8 v) {
  V16 x; x.v = v; *(uint4*)p = x.u;
}
__device__ __forceinline__ unsigned short f2bf(float f) {  // RNE float->bf16 bits
  unsigned int u = __float_as_uint(f);
  u += 0x7FFFu + ((u >> 16) & 1u);
  return (unsigned short)(u >> 16);
}
__device__ __forceinline__ float bf2f(unsigned short b) {
  return __uint_as_float(((unsigned int)b) << 16);
}
__device__ __forceinline__ f32x4 mfma16(u16x8 a, u16x8 b, f32x4 c) {
  return __builtin_amdgcn_mfma_f32_16x16x32_bf16(
      __builtin_bit_cast(bf16x8, a), __builtin_bit_cast(bf16x8, b), c, 0, 0, 0);
}

typedef __attribute__((address_space(1))) const void glob_cv;
typedef __attribute__((address_space(3))) void lds_v;
__device__ __forceinline__ void gload16(const void* g, void* l) {
  __builtin_amdgcn_global_load_lds((glob_cv*)g, (lds_v*)l, 16, 0, 0);
}

// 256-thread 64x64 bf16 tile stage with XOR group swizzle on the GLOBAL
// source (LDS dest linear, m173 pattern). 2 gload_lds per thread.
__device__ __forceinline__ void stage32(const unsigned short* __restrict__ g0,
                                        int stride, unsigned short* lds0, int tid) {
  #pragma unroll
  for (int it = 0; it < 2; ++it) {
    const int e = it * 256 + tid;            // e in [0,512)
    const int row = e >> 3, pg = e & 7;
    const int gg = pg ^ (row & 7);
    gload16(g0 + (size_t)row * stride + gg * 8, lds0 + e * 8);
  }
}

// Decode block id -> (ti: 64-row tile, sj: 128-col tile), causal.
// Row-pair p contributes 2(p+1) blocks; cumulative before p is p(p+1).
__device__ __forceinline__ void tri2_decode(int b, int& ti, int& sj) {
  int p = (int)((sqrtf(4.0f * (float)b + 1.0f) - 1.0f) * 0.5f);
  while ((p + 1) * (p + 2) <= b) ++p;
  while (p * (p + 1) > b) --p;
  const int r = b - p * (p + 1);
  if (r >= p + 1) { ti = 2 * p + 1; sj = r - (p + 1); }
  else            { ti = 2 * p;     sj = r; }
}

// ---------- prep2: invnorm + hb + hbTp + Sseg (fused prep/transp/sega) ----------
__global__ __launch_bounds__(256, 2) void k_prep2(const float* __restrict__ x,
    float* __restrict__ invnorm, unsigned short* __restrict__ hb,
    unsigned short* __restrict__ hbTp, float* __restrict__ Sseg) {
  __shared__ unsigned short Ts[32 * PSTR];   // 57.6 KB
  const int b = (int)blockIdx.x;             // rows t0..t0+31
  const int t0 = b * 32;
  const int tid = (int)threadIdx.x, wv = tid >> 6, lane = tid & 63;

  // Each wave: 8 rows. Batch all loads first (32 global loads in flight).
  float4 v[8][4];
  #pragma unroll
  for (int rr = 0; rr < 8; ++rr) {
    const int t = t0 + wv * 8 + rr;
    #pragma unroll
    for (int k = 0; k < 4; ++k) {
      const int c4 = lane + 64 * k;          // float4 index; 224 per row
      if (k < 3 || lane < 32)
        v[rr][k] = *(const float4*)(x + (size_t)t * D_ + c4 * 4);
    }
  }
  #pragma unroll
  for (int rr = 0; rr < 8; ++rr) {
    const int row = wv * 8 + rr;
    const int t = t0 + row;
    float s = 0.f;
    #pragma unroll
    for (int k = 0; k < 4; ++k)
      if (k < 3 || lane < 32)
        s += v[rr][k].x * v[rr][k].x + v[rr][k].y * v[rr][k].y +
             v[rr][k].z * v[rr][k].z + v[rr][k].w * v[rr][k].w;
    #pragma unroll
    for (int off = 32; off > 0; off >>= 1) s += __shfl_down(s, off, 64);
    const float iv = 1.0f / fmaxf(sqrtf(__shfl(s, 0, 64)), 1e-12f);
    if (lane == 0) invnorm[t] = iv;
    #pragma unroll
    for (int k = 0; k < 4; ++k) {
      const int c4 = lane + 64 * k;
      if (k < 3 || lane < 32) {
        const ushort4 o = make_ushort4(f2bf(v[rr][k].x * iv), f2bf(v[rr][k].y * iv),
                                       f2bf(v[rr][k].z * iv), f2bf(v[rr][k].w * iv));
        *(ushort4*)(hb + (size_t)t * D_ + c4 * 4) = o;
        *(ushort4*)(&Ts[row * PSTR + c4 * 4]) = o;
      }
    }
  }
  __syncthreads();

  // Sseg for segments 2b, 2b+1 (16 rows each), sega's 4-row-group order.
  for (int c = tid; c < D_; c += 256) {
    #pragma unroll
    for (int half = 0; half < 2; ++half) {
      float segsum = 0.f;
      #pragma unroll
      for (int q = 0; q < 4; ++q) {
        float gs = 0.f;
        #pragma unroll
        for (int r = 0; r < 4; ++r)
          gs += bf2f(Ts[(half * 16 + q * 4 + r) * PSTR + c]);
        segsum += gs;
      }
      Sseg[(size_t)(2 * b + half) * D_ + c] = segsum;
    }
  }

  // Transpose: hbTp[d][32 + t0 + 0..31] for all 896 d (28 tiles of 32).
  const int r = tid >> 3, c = (tid & 7) * 4;
  #pragma unroll 4
  for (int dt = 0; dt < 28; ++dt) {
    const int d = dt * 32 + r;
    const ushort4 o = make_ushort4(Ts[c * PSTR + d], Ts[(c + 1) * PSTR + d],
                                   Ts[(c + 2) * PSTR + d], Ts[(c + 3) * PSTR + d]);
    *(ushort4*)(hbTp + (size_t)d * TP + 32 + t0 + c) = o;
  }
  if (b == 0) {   // zero the 32 leading pad cols for all d rows
    for (int e = tid; e < D_ * 8; e += 256) {
      const int d = e >> 3, cc = (e & 7) * 4;
      *(ushort4*)(hbTp + (size_t)d * TP + cc) = make_ushort4(0, 0, 0, 0);
    }
  }
}

// wave-scan of 256 segments (4x64 per lane) — one column per wave
__global__ __launch_bounds__(256) void k_segb(const float* __restrict__ Sseg,
                                              float* __restrict__ Eseg) {
  const int tid = (int)threadIdx.x;
  const int wv = tid >> 6, lane = tid & 63;
  const int c = (int)blockIdx.x * 4 + wv;     // column 0..895
  float v0 = Sseg[(size_t)lane * D_ + c];
  float v1 = Sseg[(size_t)(64 + lane) * D_ + c];
  float v2 = Sseg[(size_t)(128 + lane) * D_ + c];
  float v3 = Sseg[(size_t)(192 + lane) * D_ + c];
  const float o0 = v0, o1 = v1, o2 = v2, o3 = v3;
  #pragma unroll
  for (int off = 1; off < 64; off <<= 1) {
    const float n0 = __shfl_up(v0, off, 64);
    const float n1 = __shfl_up(v1, off, 64);
    const float n2 = __shfl_up(v2, off, 64);
    const float n3 = __shfl_up(v3, off, 64);
    if (lane >= off) { v0 += n0; v1 += n1; v2 += n2; v3 += n3; }
  }
  const float tot0 = __shfl(v0, 63, 64);
  const float tot1 = __shfl(v1, 63, 64);
  const float tot2 = __shfl(v2, 63, 64);
  Eseg[(size_t)lane * D_ + c] = v0 - o0;              // exclusive
  Eseg[(size_t)(64 + lane) * D_ + c] = v1 - o1 + tot0;
  Eseg[(size_t)(128 + lane) * D_ + c] = v2 - o2 + (tot0 + tot1);
  Eseg[(size_t)(192 + lane) * D_ + c] = v3 - o3 + (tot0 + tot1 + tot2);
}

// ---------- bandw: diagonal sims (deep-MLP loads) -> weights + invL ----------
__global__ __launch_bounds__(256) void k_bandw(const unsigned short* __restrict__ hb,
    unsigned short* __restrict__ wband, float* __restrict__ invLb) {
  const int t0 = (int)blockIdx.x * 16;
  const int tid = (int)threadIdx.x;
  const int wv = tid >> 6, lane = tid & 63;
  const int tcol = lane & 15, quad = lane >> 4;
  __shared__ float sims[16][52];
  if (wv < 3) {
    const int s_base = t0 - 32 + wv * 16;
    if (s_base + 15 >= 0) {
      const int srow = max(s_base + tcol, 0);   // clamped; guarded below
      f32x4 acc = {};
      const unsigned short* arow = hb + (size_t)srow * D_ + quad * 8;
      const unsigned short* brow = hb + (size_t)(t0 + tcol) * D_ + quad * 8;
      #pragma unroll 1
      for (int c4 = 0; c4 < 4; ++c4) {          // 7 load-pairs in flight per step
        u16x8 av[7], bv[7];
        #pragma unroll
        for (int i = 0; i < 7; ++i) {
          av[i] = ld16(arow + (c4 * 7 + i) * 32);
          bv[i] = ld16(brow + (c4 * 7 + i) * 32);
        }
        #pragma unroll
        for (int i = 0; i < 7; ++i) acc = mfma16(av[i], bv[i], acc);
      }
      #pragma unroll
      for (int r = 0; r < 4; ++r)       // C[m=s_local=quad*4+r][n=t_local=tcol]
        sims[tcol][wv * 16 + quad * 4 + r] = acc[r];
    }
  }
  __syncthreads();
  if (wv == 0) {
    u16x8 af0, af1;
    float lsum = 0.f;
    #pragma unroll
    for (int j = 0; j < 8; ++j) {
      {
        const int k = quad * 8 + j;                 // k in [0,32)
        const int dt = tcol + 32 - k;               // >= 1
        const int s = t0 - 32 + k;
        unsigned short wb = 0;
        if (dt < 32 && s >= 0)
          wb = f2bf(__expf(sims[tcol][k] * (__expf(-0.1f * (float)dt) * 0.033407657f)));
        af0[j] = wb;
        lsum += bf2f(wb);
      }
      {
        const int k = 32 + quad * 8 + j;            // k in [32,64)
        const int dt = tcol + 32 - k;               // <= 15
        unsigned short wb = 0;
        if (dt >= 0)                                // k <= tcol+32 <= 47
          wb = f2bf(__expf(sims[tcol][k] * (__expf(-0.1f * (float)dt) * 0.033407657f)));
        af1[j] = wb;
        lsum += bf2f(wb);
      }
    }
    lsum += __shfl_xor(lsum, 16, 64);
    lsum += __shfl_xor(lsum, 32, 64);
    st16(wband + (size_t)(t0 + tcol) * 64 + quad * 8, af0);
    st16(wband + (size_t)(t0 + tcol) * 64 + 32 + quad * 8, af1);
    if (lane < 16) {
      const int t = t0 + lane;
      invLb[t] = 1.0f / (lsum + ((t >= 32) ? (float)(t - 31) : 0.f));
    }
  }
}

// ---------- bandg: band GEMM + in-register prefix (P eliminated) ----------
__global__ __launch_bounds__(256) void k_bandg(const unsigned short* __restrict__ hbTp,
    const unsigned short* __restrict__ wband, const float* __restrict__ invLb,
    const float* __restrict__ Eseg, const float* __restrict__ x,
    const float* __restrict__ invnorm, unsigned short* __restrict__ gb,
    float* __restrict__ gn2, float* __restrict__ dist2) {
  const int t0 = (int)blockIdx.x * 16;
  const int by = (int)blockIdx.y;             // 8 d-groups of 7 tiles
  const int tid = (int)threadIdx.x;
  const int wv = tid >> 6, lane = tid & 63;
  const int tcol = lane & 15, quad = lane >> 4;
  const u16x8 af0 = ld16(wband + (size_t)(t0 + tcol) * 64 + quad * 8);
  const u16x8 af1 = ld16(wband + (size_t)(t0 + tcol) * 64 + 32 + quad * 8);
  const int sg = (t0 >> 4) - 2;               // segment of rows t0-32..t0-17
  float invLr[4], inrr[4];
  #pragma unroll
  for (int r = 0; r < 4; ++r) {
    const int tt = t0 + quad * 4 + r;
    invLr[r] = invLb[tt];
    inrr[r]  = invnorm[tt];
  }
  float sgl[4] = {0.f, 0.f, 0.f, 0.f}, sdl[4] = {0.f, 0.f, 0.f, 0.f};
  for (int i = wv; i < 7; i += 4) {
    const int d = (by * 7 + i) * 16 + tcol;
    const unsigned short* brow = hbTp + (size_t)d * TP + t0 + quad * 8;
    const u16x8 b0 = ld16(brow);          // k in [0,32): zeros where s<0
    const u16x8 b1 = ld16(brow + 32);     // k in [32,64): tail x w=0 harmless
    f32x4 C = {};
    C = mfma16(af0, b0, C);
    C = mfma16(af1, b1, C);
    // P(t0-32+j) recomputed in-register: Eseg[sg][d] + sequential bf16 adds
    // over hbTp[d][t0 .. t0+15] (rows t0-32..t0-17). Same f32 order as the
    // old k_segc -> bit-identical.
    float pr[4] = {0.f, 0.f, 0.f, 0.f};
    if (t0 >= 32) {
      const unsigned short* prow = hbTp + (size_t)d * TP + t0;
      const uint4 w0 = *(const uint4*)prow;
      const uint4 w1 = *(const uint4*)(prow + 8);
      const unsigned int wz[8] = {w0.x, w0.y, w0.z, w0.w, w1.x, w1.y, w1.z, w1.w};
      float run = Eseg[(size_t)sg * D_ + d];
      #pragma unroll
      for (int jj = 0; jj < 16; ++jj) {
        const unsigned int uu = wz[jj >> 1];
        const unsigned short hh =
            (jj & 1) ? (unsigned short)(uu >> 16) : (unsigned short)(uu & 0xffffu);
        run += bf2f(hh);
        if ((jj >> 2) == quad) pr[jj & 3] = run;
      }
    }
    #pragma unroll
    for (int r = 0; r < 4; ++r) {     // C[m=quad*4+r -> t][n=tcol -> d]
      const int tt = t0 + quad * 4 + r;
      float gacc = C[r];
      if (tt >= 32) gacc += pr[r];
      const float g = gacc * invLr[r];
      gb[(size_t)tt * D_ + d] = f2bf(g);
      const float e = x[(size_t)tt * D_ + d] * inrr[r] - g;
      sgl[r] += g * g;
      sdl[r] += e * e;
    }
  }
  #pragma unroll
  for (int r = 0; r < 4; ++r) {
    float sg2 = sgl[r], sd = sdl[r];
    sg2 += __shfl_xor(sg2, 1, 64); sg2 += __shfl_xor(sg2, 2, 64);
    sg2 += __shfl_xor(sg2, 4, 64); sg2 += __shfl_xor(sg2, 8, 64);
    sd += __shfl_xor(sd, 1, 64); sd += __shfl_xor(sd, 2, 64);
    sd += __shfl_xor(sd, 4, 64); sd += __shfl_xor(sd, 8, 64);
    if (tcol == 0) {
      atomicAdd(&gn2[t0 + quad * 4 + r], sg2);
      atomicAdd(&dist2[t0 + quad * 4 + r], sd);
    }
  }
}

// ---------- GEMM3: cross = g h^T, 64x128 causal tiles (1056 blocks); row-max ----------
// v10 config (best measured): 4 waves x (64 rows x 32 cols), per ks 6
// ds_read_b128 feed 8 MFMA; 24.3 KB LDS -> 6 blocks/CU.
__global__ __launch_bounds__(256, 5) void k_gemm3(const unsigned short* __restrict__ gb,
    const unsigned short* __restrict__ hb, const float* __restrict__ gn2,
    unsigned int* __restrict__ dmaxu) {
  // Bijective XCD swizzle: 1056 = 8*132.
  const int bswz = ((int)blockIdx.x & 7) * 132 + ((int)blockIdx.x >> 3);
  int ti, sj;
  tri2_decode(bswz, ti, sj);
  const int t0 = ti * 64, s0 = sj * 128;
  __shared__ unsigned short As[64 * 64];    // 8 KB  (t rows)
  __shared__ unsigned short Bs[128 * 64];   // 16 KB (s rows)
  __shared__ unsigned int dmx[64];          // per-block row-max merge
  const int tid = (int)threadIdx.x;
  const int lane = tid & 63, wv = tid >> 6;
  const int tcol = lane & 15, quad = lane >> 4;
  if (tid < 64) dmx[tid] = 0u;
  f32x4 acc[4][2] = {};

  for (int kc = 0; kc < 14; ++kc) {
    __syncthreads();   // prev chunk's reads done before overwrite (also fences dmx init)
    stage32(gb + (size_t)t0 * D_ + kc * 64, D_, As, tid);
    stage32(hb + (size_t)s0 * D_ + kc * 64, D_, Bs, tid);
    stage32(hb + (size_t)(s0 + 64) * D_ + kc * 64, D_, Bs + 64 * 64, tid);
    __syncthreads();   // staged data visible
    #pragma unroll
    for (int ks = 0; ks < 2; ++ks) {
      const int go = ((ks * 4 + quad) ^ (tcol & 7)) * 8;
      u16x8 bf[2], af[4];
      #pragma unroll
      for (int ni = 0; ni < 2; ++ni)
        bf[ni] = ld16(&Bs[(wv * 32 + ni * 16 + tcol) * 64 + go]);
      #pragma unroll
      for (int mi = 0; mi < 4; ++mi)
        af[mi] = ld16(&As[(mi * 16 + tcol) * 64 + go]);
      #pragma unroll
      for (int mi = 0; mi < 4; ++mi)
        #pragma unroll
        for (int ni = 0; ni < 2; ++ni)
          acc[mi][ni] = mfma16(af[mi], bf[ni], acc[mi][ni]);
    }
  }

  // epilogue: m2[t] = max over this wave's 32-col strip, merge in LDS, then global
  #pragma unroll
  for (int mi = 0; mi < 4; ++mi) {
    #pragma unroll
    for (int r = 0; r < 4; ++r) {
      const int t = t0 + mi * 16 + quad * 4 + r;
      const float gn = gn2[t];
      float m2 = 0.f;
      #pragma unroll
      for (int ni = 0; ni < 2; ++ni) {
        const int s = s0 + wv * 32 + ni * 16 + tcol;
        if (t >= s)
          m2 = fmaxf(m2, fmaxf(1.0f - 2.0f * acc[mi][ni][r] + gn, 1e-24f));
      }
      m2 = fmaxf(m2, __shfl_xor(m2, 1, 64));
      m2 = fmaxf(m2, __shfl_xor(m2, 2, 64));
      m2 = fmaxf(m2, __shfl_xor(m2, 4, 64));
      m2 = fmaxf(m2, __shfl_xor(m2, 8, 64));
      if (tcol == 0 && m2 > 0.f)
        atomicMax(&dmx[mi * 16 + quad * 4 + r], __float_as_uint(m2));
    }
  }
  __syncthreads();
  if (tid < 64) {
    const unsigned int v = dmx[tid];
    if (v) atomicMax(&dmaxu[t0 + tid], v);
  }
}

__global__ __launch_bounds__(256) void k_final(const float* __restrict__ m_t,
    const float* __restrict__ c_t, const float* __restrict__ d_t,
    const float* __restrict__ mu, const float* __restrict__ dist2,
    const unsigned int* __restrict__ dmaxu, float* __restrict__ out) {
  const int t = (int)blockIdx.x * 256 + (int)threadIdx.x;
  if (t >= T_) return;
  float ratio;
  if (t == 0) {
    ratio = 0.f;  // ref: dist~1e-12, dist_max<1e-6 -> 1.0 => ratio ~0
  } else {
    float dmax = sqrtf(__uint_as_float(dmaxu[t]));
    if (dmax < 1e-6f) dmax = 1.0f;
    ratio = sqrtf(fmaxf(dist2[t], 1e-24f)) / (dmax + 1e-8f);
  }
  const float stab = 1.0f - 0.3f * c_t[t] + 0.2f * d_t[t];
  const float xi = 1.0f - mu[0] * m_t[t];
  out[t] = fminf(fmaxf(ratio * stab * xi, 0.f), 1.f);
}

extern "C" void kernel_launch(void* const* d_in, const int* in_sizes, int n_in,
                              void* d_out, int out_size, void* d_ws, size_t ws_size,
                              hipStream_t stream) {
  const float* x   = (const float*)d_in[0];
  const float* m_t = (const float*)d_in[1];
  const float* c_t = (const float*)d_in[2];
  const float* d_t = (const float*)d_in[3];
  const float* mu  = (const float*)d_in[4];
  float* out = (float*)d_out;

  float* ws = (float*)d_ws;
  float* invnorm = ws;                                          // [T]
  unsigned int* dmaxu = (unsigned int*)(ws + (size_t)T_);       // [T]
  float* gn2     = ws + 2 * (size_t)T_;                         // [T]
  float* dist2   = ws + 3 * (size_t)T_;                         // [T]
  float* invLb   = ws + 4 * (size_t)T_;                         // [T]
  float* Sseg    = ws + 5 * (size_t)T_;                         // [256*D]
  float* Eseg    = Sseg + 256 * (size_t)D_;                     // [256*D]
  float* P       = Eseg + 256 * (size_t)D_;                     // (unused region)
  unsigned short* hb    = (unsigned short*)(P + (size_t)T_ * D_);  // [T*D]
  unsigned short* hbTp  = hb + (size_t)T_ * D_;                    // [D*(T+64)]
  unsigned short* gb    = hbTp + (size_t)D_ * TP;                  // [T*D]
  unsigned short* wband = gb + (size_t)T_ * D_;                    // [T*64]

  // zero dmaxu + gn2 + dist2 (contiguous 3T words)
  hipMemsetAsync(dmaxu, 0, 3 * (size_t)T_ * sizeof(unsigned int), stream);

  k_prep2<<<T_ / 32, 256, 0, stream>>>(x, invnorm, hb, hbTp, Sseg);
  k_segb<<<224, 256, 0, stream>>>(Sseg, Eseg);
  k_bandw<<<T_ / 16, 256, 0, stream>>>(hb, wband, invLb);
  k_bandg<<<dim3(T_ / 16, 8), 256, 0, stream>>>(hbTp, wband, invLb, Eseg, x, invnorm,
                                                gb, gn2, dist2);
  k_gemm3<<<1056, 256, 0, stream>>>(gb, hb, gn2, dmaxu);
  k_final<<<(T_ + 255) / 256, 256, 0, stream>>>(m_t, c_t, d_t, mu, dist2, dmaxu, out);
}

// Round 8
// 137.847 us; speedup vs baseline: 1.0394x; 1.0331x over previous
//
#include <hip/hip_runtime.h>
#include <math.h>

// SemanticDriftCoeff — band+prefix, v13r: identical resubmit of v13 (R7 was
// an infra failure — "container failed twice", no kernel signal).
// (a) k_prep2 re-gridded 128x32rows -> 256x16rows (28.8KB LDS, every CU
//     busy; v12's 128-block version left half the GPU idle -> fusion win
//     was cancelled). Sseg now 1 segment/block, same f32 order.
// (b) dmaxu/gn2/dist2 zeroing folded into k_prep2 (blocks 0-47); the
//     hipMemsetAsync dispatch is dropped (6 launches total).
// (c) k_bandg in-register prefix (P eliminated) and k_gemm3 v10 config
//     (64x128 tile, 4 waves x 64x32, 1056 = 8*132 blocks) unchanged.
// ws: invnorm[T], dmaxu[T], gn2[T], dist2[T], invLb[T], Sseg[256*D],
// Eseg[256*D]; hb[T*D], hbTp[D*(T+64)], gb[T*D], wband[T*64] bf16.

#define T_ 4096
#define D_ 896
#define TP (T_ + 64)   // padded hbTp row stride (ushorts)
#define PSTR 900       // k_prep2 LDS row stride (ushorts), mult of 4, bank-spread

typedef float f32x4 __attribute__((ext_vector_type(4)));
typedef unsigned short u16x8 __attribute__((ext_vector_type(8)));
typedef __bf16 bf16x8 __attribute__((ext_vector_type(8)));

union V16 { uint4 u; u16x8 v; };

__device__ __forceinline__ u16x8 ld16(const unsigned short* p) {
  V16 x; x.u = *(const uint4*)p; return x.v;
}
__device__ __forceinline__ void st16(unsigned short* p, u16x8 v) {
  V16 x; x.v = v; *(uint4*)p = x.u;
}
__device__ __forceinline__ unsigned short f2bf(float f) {  // RNE float->bf16 bits
  unsigned int u = __float_as_uint(f);
  u += 0x7FFFu + ((u >> 16) & 1u);
  return (unsigned short)(u >> 16);
}
__device__ __forceinline__ float bf2f(unsigned short b) {
  return __uint_as_float(((unsigned int)b) << 16);
}
__device__ __forceinline__ f32x4 mfma16(u16x8 a, u16x8 b, f32x4 c) {
  return __builtin_amdgcn_mfma_f32_16x16x32_bf16(
      __builtin_bit_cast(bf16x8, a), __builtin_bit_cast(bf16x8, b), c, 0, 0, 0);
}

typedef __attribute__((address_space(1))) const void glob_cv;
typedef __attribute__((address_space(3))) void lds_v;
__device__ __forceinline__ void gload16(const void* g, void* l) {
  __builtin_amdgcn_global_load_lds((glob_cv*)g, (lds_v*)l, 16, 0, 0);
}

// 256-thread 64x64 bf16 tile stage with XOR group swizzle on the GLOBAL
// source (LDS dest linear, m173 pattern). 2 gload_lds per thread.
__device__ __forceinline__ void stage32(const unsigned short* __restrict__ g0,
                                        int stride, unsigned short* lds0, int tid) {
  #pragma unroll
  for (int it = 0; it < 2; ++it) {
    const int e = it * 256 + tid;            // e in [0,512)
    const int row = e >> 3, pg = e & 7;
    const int gg = pg ^ (row & 7);
    gload16(g0 + (size_t)row * stride + gg * 8, lds0 + e * 8);
  }
}

// Decode block id -> (ti: 64-row tile, sj: 128-col tile), causal.
// Row-pair p contributes 2(p+1) blocks; cumulative before p is p(p+1).
__device__ __forceinline__ void tri2_decode(int b, int& ti, int& sj) {
  int p = (int)((sqrtf(4.0f * (float)b + 1.0f) - 1.0f) * 0.5f);
  while ((p + 1) * (p + 2) <= b) ++p;
  while (p * (p + 1) > b) --p;
  const int r = b - p * (p + 1);
  if (r >= p + 1) { ti = 2 * p + 1; sj = r - (p + 1); }
  else            { ti = 2 * p;     sj = r; }
}

// ---------- prep2: invnorm + hb + hbTp + Sseg + ws zeroing (fused) ----------
__global__ __launch_bounds__(256, 2) void k_prep2(const float* __restrict__ x,
    float* __restrict__ invnorm, unsigned short* __restrict__ hb,
    unsigned short* __restrict__ hbTp, float* __restrict__ Sseg,
    float* __restrict__ zero3) {
  __shared__ unsigned short Ts[16 * PSTR];   // 28.8 KB
  const int b = (int)blockIdx.x;             // rows t0..t0+15 == segment b
  const int t0 = b * 16;
  const int tid = (int)threadIdx.x, wv = tid >> 6, lane = tid & 63;

  // zero dmaxu+gn2+dist2 (3T = 12288 words) from blocks 0..47
  if (b < 48) zero3[b * 256 + tid] = 0.f;

  // Each wave: 4 rows. Batch loads first (16 global loads in flight).
  float4 v[4][4];
  #pragma unroll
  for (int rr = 0; rr < 4; ++rr) {
    const int t = t0 + wv * 4 + rr;
    #pragma unroll
    for (int k = 0; k < 4; ++k) {
      const int c4 = lane + 64 * k;          // float4 index; 224 per row
      if (k < 3 || lane < 32)
        v[rr][k] = *(const float4*)(x + (size_t)t * D_ + c4 * 4);
    }
  }
  #pragma unroll
  for (int rr = 0; rr < 4; ++rr) {
    const int row = wv * 4 + rr;
    const int t = t0 + row;
    float s = 0.f;
    #pragma unroll
    for (int k = 0; k < 4; ++k)
      if (k < 3 || lane < 32)
        s += v[rr][k].x * v[rr][k].x + v[rr][k].y * v[rr][k].y +
             v[rr][k].z * v[rr][k].z + v[rr][k].w * v[rr][k].w;
    #pragma unroll
    for (int off = 32; off > 0; off >>= 1) s += __shfl_down(s, off, 64);
    const float iv = 1.0f / fmaxf(sqrtf(__shfl(s, 0, 64)), 1e-12f);
    if (lane == 0) invnorm[t] = iv;
    #pragma unroll
    for (int k = 0; k < 4; ++k) {
      const int c4 = lane + 64 * k;
      if (k < 3 || lane < 32) {
        const ushort4 o = make_ushort4(f2bf(v[rr][k].x * iv), f2bf(v[rr][k].y * iv),
                                       f2bf(v[rr][k].z * iv), f2bf(v[rr][k].w * iv));
        *(ushort4*)(hb + (size_t)t * D_ + c4 * 4) = o;
        *(ushort4*)(&Ts[row * PSTR + c4 * 4]) = o;
      }
    }
  }
  __syncthreads();

  // Sseg[b][c]: sum of the 16 rows in 4-row groups, left-assoc (sega order).
  for (int c = tid; c < D_; c += 256) {
    float segsum = 0.f;
    #pragma unroll
    for (int q = 0; q < 4; ++q) {
      float gs = 0.f;
      #pragma unroll
      for (int r = 0; r < 4; ++r)
        gs += bf2f(Ts[(q * 4 + r) * PSTR + c]);
      segsum += gs;
    }
    Sseg[(size_t)b * D_ + c] = segsum;
  }

  // Transpose: hbTp[d][32 + t0 + 0..15] for all 896 d. 3584 ushort4 stores.
  #pragma unroll 2
  for (int it = 0; it < 14; ++it) {
    const int e = it * 256 + tid;            // 0..3583
    const int d = e >> 2, q = e & 3;
    const ushort4 o = make_ushort4(Ts[(q * 4 + 0) * PSTR + d],
                                   Ts[(q * 4 + 1) * PSTR + d],
                                   Ts[(q * 4 + 2) * PSTR + d],
                                   Ts[(q * 4 + 3) * PSTR + d]);
    *(ushort4*)(hbTp + (size_t)d * TP + 32 + t0 + q * 4) = o;
  }
  if (b == 0) {   // zero the 32 leading pad cols for all d rows
    for (int e = tid; e < D_ * 8; e += 256) {
      const int d = e >> 3, cc = (e & 7) * 4;
      *(ushort4*)(hbTp + (size_t)d * TP + cc) = make_ushort4(0, 0, 0, 0);
    }
  }
}

// wave-scan of 256 segments (4x64 per lane) — one column per wave
__global__ __launch_bounds__(256) void k_segb(const float* __restrict__ Sseg,
                                              float* __restrict__ Eseg) {
  const int tid = (int)threadIdx.x;
  const int wv = tid >> 6, lane = tid & 63;
  const int c = (int)blockIdx.x * 4 + wv;     // column 0..895
  float v0 = Sseg[(size_t)lane * D_ + c];
  float v1 = Sseg[(size_t)(64 + lane) * D_ + c];
  float v2 = Sseg[(size_t)(128 + lane) * D_ + c];
  float v3 = Sseg[(size_t)(192 + lane) * D_ + c];
  const float o0 = v0, o1 = v1, o2 = v2, o3 = v3;
  #pragma unroll
  for (int off = 1; off < 64; off <<= 1) {
    const float n0 = __shfl_up(v0, off, 64);
    const float n1 = __shfl_up(v1, off, 64);
    const float n2 = __shfl_up(v2, off, 64);
    const float n3 = __shfl_up(v3, off, 64);
    if (lane >= off) { v0 += n0; v1 += n1; v2 += n2; v3 += n3; }
  }
  const float tot0 = __shfl(v0, 63, 64);
  const float tot1 = __shfl(v1, 63, 64);
  const float tot2 = __shfl(v2, 63, 64);
  Eseg[(size_t)lane * D_ + c] = v0 - o0;              // exclusive
  Eseg[(size_t)(64 + lane) * D_ + c] = v1 - o1 + tot0;
  Eseg[(size_t)(128 + lane) * D_ + c] = v2 - o2 + (tot0 + tot1);
  Eseg[(size_t)(192 + lane) * D_ + c] = v3 - o3 + (tot0 + tot1 + tot2);
}

// ---------- bandw: diagonal sims (deep-MLP loads) -> weights + invL ----------
__global__ __launch_bounds__(256) void k_bandw(const unsigned short* __restrict__ hb,
    unsigned short* __restrict__ wband, float* __restrict__ invLb) {
  const int t0 = (int)blockIdx.x * 16;
  const int tid = (int)threadIdx.x;
  const int wv = tid >> 6, lane = tid & 63;
  const int tcol = lane & 15, quad = lane >> 4;
  __shared__ float sims[16][52];
  if (wv < 3) {
    const int s_base = t0 - 32 + wv * 16;
    if (s_base + 15 >= 0) {
      const int srow = max(s_base + tcol, 0);   // clamped; guarded below
      f32x4 acc = {};
      const unsigned short* arow = hb + (size_t)srow * D_ + quad * 8;
      const unsigned short* brow = hb + (size_t)(t0 + tcol) * D_ + quad * 8;
      #pragma unroll 1
      for (int c4 = 0; c4 < 4; ++c4) {          // 7 load-pairs in flight per step
        u16x8 av[7], bv[7];
        #pragma unroll
        for (int i = 0; i < 7; ++i) {
          av[i] = ld16(arow + (c4 * 7 + i) * 32);
          bv[i] = ld16(brow + (c4 * 7 + i) * 32);
        }
        #pragma unroll
        for (int i = 0; i < 7; ++i) acc = mfma16(av[i], bv[i], acc);
      }
      #pragma unroll
      for (int r = 0; r < 4; ++r)       // C[m=s_local=quad*4+r][n=t_local=tcol]
        sims[tcol][wv * 16 + quad * 4 + r] = acc[r];
    }
  }
  __syncthreads();
  if (wv == 0) {
    u16x8 af0, af1;
    float lsum = 0.f;
    #pragma unroll
    for (int j = 0; j < 8; ++j) {
      {
        const int k = quad * 8 + j;                 // k in [0,32)
        const int dt = tcol + 32 - k;               // >= 1
        const int s = t0 - 32 + k;
        unsigned short wb = 0;
        if (dt < 32 && s >= 0)
          wb = f2bf(__expf(sims[tcol][k] * (__expf(-0.1f * (float)dt) * 0.033407657f)));
        af0[j] = wb;
        lsum += bf2f(wb);
      }
      {
        const int k = 32 + quad * 8 + j;            // k in [32,64)
        const int dt = tcol + 32 - k;               // <= 15
        unsigned short wb = 0;
        if (dt >= 0)                                // k <= tcol+32 <= 47
          wb = f2bf(__expf(sims[tcol][k] * (__expf(-0.1f * (float)dt) * 0.033407657f)));
        af1[j] = wb;
        lsum += bf2f(wb);
      }
    }
    lsum += __shfl_xor(lsum, 16, 64);
    lsum += __shfl_xor(lsum, 32, 64);
    st16(wband + (size_t)(t0 + tcol) * 64 + quad * 8, af0);
    st16(wband + (size_t)(t0 + tcol) * 64 + 32 + quad * 8, af1);
    if (lane < 16) {
      const int t = t0 + lane;
      invLb[t] = 1.0f / (lsum + ((t >= 32) ? (float)(t - 31) : 0.f));
    }
  }
}

// ---------- bandg: band GEMM + in-register prefix (P eliminated) ----------
__global__ __launch_bounds__(256) void k_bandg(const unsigned short* __restrict__ hbTp,
    const unsigned short* __restrict__ wband, const float* __restrict__ invLb,
    const float* __restrict__ Eseg, const float* __restrict__ x,
    const float* __restrict__ invnorm, unsigned short* __restrict__ gb,
    float* __restrict__ gn2, float* __restrict__ dist2) {
  const int t0 = (int)blockIdx.x * 16;
  const int by = (int)blockIdx.y;             // 8 d-groups of 7 tiles
  const int tid = (int)threadIdx.x;
  const int wv = tid >> 6, lane = tid & 63;
  const int tcol = lane & 15, quad = lane >> 4;
  const u16x8 af0 = ld16(wband + (size_t)(t0 + tcol) * 64 + quad * 8);
  const u16x8 af1 = ld16(wband + (size_t)(t0 + tcol) * 64 + 32 + quad * 8);
  const int sg = (t0 >> 4) - 2;               // segment of rows t0-32..t0-17
  float invLr[4], inrr[4];
  #pragma unroll
  for (int r = 0; r < 4; ++r) {
    const int tt = t0 + quad * 4 + r;
    invLr[r] = invLb[tt];
    inrr[r]  = invnorm[tt];
  }
  float sgl[4] = {0.f, 0.f, 0.f, 0.f}, sdl[4] = {0.f, 0.f, 0.f, 0.f};
  for (int i = wv; i < 7; i += 4) {
    const int d = (by * 7 + i) * 16 + tcol;
    const unsigned short* brow = hbTp + (size_t)d * TP + t0 + quad * 8;
    const u16x8 b0 = ld16(brow);          // k in [0,32): zeros where s<0
    const u16x8 b1 = ld16(brow + 32);     // k in [32,64): tail x w=0 harmless
    f32x4 C = {};
    C = mfma16(af0, b0, C);
    C = mfma16(af1, b1, C);
    // P(t0-32+j) recomputed in-register: Eseg[sg][d] + sequential bf16 adds
    // over hbTp[d][t0 .. t0+15] (rows t0-32..t0-17). Same f32 order as the
    // old k_segc -> bit-identical.
    float pr[4] = {0.f, 0.f, 0.f, 0.f};
    if (t0 >= 32) {
      const unsigned short* prow = hbTp + (size_t)d * TP + t0;
      const uint4 w0 = *(const uint4*)prow;
      const uint4 w1 = *(const uint4*)(prow + 8);
      const unsigned int wz[8] = {w0.x, w0.y, w0.z, w0.w, w1.x, w1.y, w1.z, w1.w};
      float run = Eseg[(size_t)sg * D_ + d];
      #pragma unroll
      for (int jj = 0; jj < 16; ++jj) {
        const unsigned int uu = wz[jj >> 1];
        const unsigned short hh =
            (jj & 1) ? (unsigned short)(uu >> 16) : (unsigned short)(uu & 0xffffu);
        run += bf2f(hh);
        if ((jj >> 2) == quad) pr[jj & 3] = run;
      }
    }
    #pragma unroll
    for (int r = 0; r < 4; ++r) {     // C[m=quad*4+r -> t][n=tcol -> d]
      const int tt = t0 + quad * 4 + r;
      float gacc = C[r];
      if (tt >= 32) gacc += pr[r];
      const float g = gacc * invLr[r];
      gb[(size_t)tt * D_ + d] = f2bf(g);
      const float e = x[(size_t)tt * D_ + d] * inrr[r] - g;
      sgl[r] += g * g;
      sdl[r] += e * e;
    }
  }
  #pragma unroll
  for (int r = 0; r < 4; ++r) {
    float sg2 = sgl[r], sd = sdl[r];
    sg2 += __shfl_xor(sg2, 1, 64); sg2 += __shfl_xor(sg2, 2, 64);
    sg2 += __shfl_xor(sg2, 4, 64); sg2 += __shfl_xor(sg2, 8, 64);
    sd += __shfl_xor(sd, 1, 64); sd += __shfl_xor(sd, 2, 64);
    sd += __shfl_xor(sd, 4, 64); sd += __shfl_xor(sd, 8, 64);
    if (tcol == 0) {
      atomicAdd(&gn2[t0 + quad * 4 + r], sg2);
      atomicAdd(&dist2[t0 + quad * 4 + r], sd);
    }
  }
}

// ---------- GEMM3: cross = g h^T, 64x128 causal tiles (1056 blocks); row-max ----------
// v10 config (best measured): 4 waves x (64 rows x 32 cols), per ks 6
// ds_read_b128 feed 8 MFMA; 24.3 KB LDS -> 6 blocks/CU.
__global__ __launch_bounds__(256, 5) void k_gemm3(const unsigned short* __restrict__ gb,
    const unsigned short* __restrict__ hb, const float* __restrict__ gn2,
    unsigned int* __restrict__ dmaxu) {
  // Bijective XCD swizzle: 1056 = 8*132.
  const int bswz = ((int)blockIdx.x & 7) * 132 + ((int)blockIdx.x >> 3);
  int ti, sj;
  tri2_decode(bswz, ti, sj);
  const int t0 = ti * 64, s0 = sj * 128;
  __shared__ unsigned short As[64 * 64];    // 8 KB  (t rows)
  __shared__ unsigned short Bs[128 * 64];   // 16 KB (s rows)
  __shared__ unsigned int dmx[64];          // per-block row-max merge
  const int tid = (int)threadIdx.x;
  const int lane = tid & 63, wv = tid >> 6;
  const int tcol = lane & 15, quad = lane >> 4;
  if (tid < 64) dmx[tid] = 0u;
  f32x4 acc[4][2] = {};

  for (int kc = 0; kc < 14; ++kc) {
    __syncthreads();   // prev chunk's reads done before overwrite (also fences dmx init)
    stage32(gb + (size_t)t0 * D_ + kc * 64, D_, As, tid);
    stage32(hb + (size_t)s0 * D_ + kc * 64, D_, Bs, tid);
    stage32(hb + (size_t)(s0 + 64) * D_ + kc * 64, D_, Bs + 64 * 64, tid);
    __syncthreads();   // staged data visible
    #pragma unroll
    for (int ks = 0; ks < 2; ++ks) {
      const int go = ((ks * 4 + quad) ^ (tcol & 7)) * 8;
      u16x8 bf[2], af[4];
      #pragma unroll
      for (int ni = 0; ni < 2; ++ni)
        bf[ni] = ld16(&Bs[(wv * 32 + ni * 16 + tcol) * 64 + go]);
      #pragma unroll
      for (int mi = 0; mi < 4; ++mi)
        af[mi] = ld16(&As[(mi * 16 + tcol) * 64 + go]);
      #pragma unroll
      for (int mi = 0; mi < 4; ++mi)
        #pragma unroll
        for (int ni = 0; ni < 2; ++ni)
          acc[mi][ni] = mfma16(af[mi], bf[ni], acc[mi][ni]);
    }
  }

  // epilogue: m2[t] = max over this wave's 32-col strip, merge in LDS, then global
  #pragma unroll
  for (int mi = 0; mi < 4; ++mi) {
    #pragma unroll
    for (int r = 0; r < 4; ++r) {
      const int t = t0 + mi * 16 + quad * 4 + r;
      const float gn = gn2[t];
      float m2 = 0.f;
      #pragma unroll
      for (int ni = 0; ni < 2; ++ni) {
        const int s = s0 + wv * 32 + ni * 16 + tcol;
        if (t >= s)
          m2 = fmaxf(m2, fmaxf(1.0f - 2.0f * acc[mi][ni][r] + gn, 1e-24f));
      }
      m2 = fmaxf(m2, __shfl_xor(m2, 1, 64));
      m2 = fmaxf(m2, __shfl_xor(m2, 2, 64));
      m2 = fmaxf(m2, __shfl_xor(m2, 4, 64));
      m2 = fmaxf(m2, __shfl_xor(m2, 8, 64));
      if (tcol == 0 && m2 > 0.f)
        atomicMax(&dmx[mi * 16 + quad * 4 + r], __float_as_uint(m2));
    }
  }
  __syncthreads();
  if (tid < 64) {
    const unsigned int v = dmx[tid];
    if (v) atomicMax(&dmaxu[t0 + tid], v);
  }
}

__global__ __launch_bounds__(256) void k_final(const float* __restrict__ m_t,
    const float* __restrict__ c_t, const float* __restrict__ d_t,
    const float* __restrict__ mu, const float* __restrict__ dist2,
    const unsigned int* __restrict__ dmaxu, float* __restrict__ out) {
  const int t = (int)blockIdx.x * 256 + (int)threadIdx.x;
  if (t >= T_) return;
  float ratio;
  if (t == 0) {
    ratio = 0.f;  // ref: dist~1e-12, dist_max<1e-6 -> 1.0 => ratio ~0
  } else {
    float dmax = sqrtf(__uint_as_float(dmaxu[t]));
    if (dmax < 1e-6f) dmax = 1.0f;
    ratio = sqrtf(fmaxf(dist2[t], 1e-24f)) / (dmax + 1e-8f);
  }
  const float stab = 1.0f - 0.3f * c_t[t] + 0.2f * d_t[t];
  const float xi = 1.0f - mu[0] * m_t[t];
  out[t] = fminf(fmaxf(ratio * stab * xi, 0.f), 1.f);
}

extern "C" void kernel_launch(void* const* d_in, const int* in_sizes, int n_in,
                              void* d_out, int out_size, void* d_ws, size_t ws_size,
                              hipStream_t stream) {
  const float* x   = (const float*)d_in[0];
  const float* m_t = (const float*)d_in[1];
  const float* c_t = (const float*)d_in[2];
  const float* d_t = (const float*)d_in[3];
  const float* mu  = (const float*)d_in[4];
  float* out = (float*)d_out;

  float* ws = (float*)d_ws;
  float* invnorm = ws;                                          // [T]
  unsigned int* dmaxu = (unsigned int*)(ws + (size_t)T_);       // [T]
  float* gn2     = ws + 2 * (size_t)T_;                         // [T]
  float* dist2   = ws + 3 * (size_t)T_;                         // [T]
  float* invLb   = ws + 4 * (size_t)T_;                         // [T]
  float* Sseg    = ws + 5 * (size_t)T_;                         // [256*D]
  float* Eseg    = Sseg + 256 * (size_t)D_;                     // [256*D]
  float* Pold    = Eseg + 256 * (size_t)D_;                     // (unused region)
  unsigned short* hb    = (unsigned short*)(Pold + (size_t)T_ * D_);  // [T*D]
  unsigned short* hbTp  = hb + (size_t)T_ * D_;                    // [D*(T+64)]
  unsigned short* gb    = hbTp + (size_t)D_ * TP;                  // [T*D]
  unsigned short* wband = gb + (size_t)T_ * D_;                    // [T*64]

  float* zero3 = ws + (size_t)T_;   // dmaxu+gn2+dist2, zeroed inside k_prep2

  k_prep2<<<T_ / 16, 256, 0, stream>>>(x, invnorm, hb, hbTp, Sseg, zero3);
  k_segb<<<224, 256, 0, stream>>>(Sseg, Eseg);
  k_bandw<<<T_ / 16, 256, 0, stream>>>(hb, wband, invLb);
  k_bandg<<<dim3(T_ / 16, 8), 256, 0, stream>>>(hbTp, wband, invLb, Eseg, x, invnorm,
                                                gb, gn2, dist2);
  k_gemm3<<<1056, 256, 0, stream>>>(gb, hb, gn2, dmaxu);
  k_final<<<(T_ + 255) / 256, 256, 0, stream>>>(m_t, c_t, d_t, mu, dist2, dmaxu, out);
}

// Round 9
// 135.605 us; speedup vs baseline: 1.0565x; 1.0165x over previous
//
#include <hip/hip_runtime.h>
#include <math.h>

// SemanticDriftCoeff — band+prefix, v14: k_segb folded into k_bandw's idle
// wave 3 (phase 1 uses waves 0-2 for sims; wave 3 now runs the 4-column
// Kogge-Stone scan for block b<224, finishing under phase 1's loads before
// the existing barrier). 6 -> 5 launches; segb wall-clock -> ~0.
// All arithmetic bit-identical to v13 (best: 137.8 us).
// k_prep2 (256x16rows, fused zeroing), k_bandg (in-register prefix),
// k_gemm3 (v10 config: 64x128 tile, 4 waves x 64x32, 1056 = 8*132 blocks),
// k_final unchanged.
// ws: invnorm[T], dmaxu[T], gn2[T], dist2[T], invLb[T], Sseg[256*D],
// Eseg[256*D]; hb[T*D], hbTp[D*(T+64)], gb[T*D], wband[T*64] bf16.

#define T_ 4096
#define D_ 896
#define TP (T_ + 64)   // padded hbTp row stride (ushorts)
#define PSTR 900       // k_prep2 LDS row stride (ushorts), mult of 4, bank-spread

typedef float f32x4 __attribute__((ext_vector_type(4)));
typedef unsigned short u16x8 __attribute__((ext_vector_type(8)));
typedef __bf16 bf16x8 __attribute__((ext_vector_type(8)));

union V16 { uint4 u; u16x8 v; };

__device__ __forceinline__ u16x8 ld16(const unsigned short* p) {
  V16 x; x.u = *(const uint4*)p; return x.v;
}
__device__ __forceinline__ void st16(unsigned short* p, u16x8 v) {
  V16 x; x.v = v; *(uint4*)p = x.u;
}
__device__ __forceinline__ unsigned short f2bf(float f) {  // RNE float->bf16 bits
  unsigned int u = __float_as_uint(f);
  u += 0x7FFFu + ((u >> 16) & 1u);
  return (unsigned short)(u >> 16);
}
__device__ __forceinline__ float bf2f(unsigned short b) {
  return __uint_as_float(((unsigned int)b) << 16);
}
__device__ __forceinline__ f32x4 mfma16(u16x8 a, u16x8 b, f32x4 c) {
  return __builtin_amdgcn_mfma_f32_16x16x32_bf16(
      __builtin_bit_cast(bf16x8, a), __builtin_bit_cast(bf16x8, b), c, 0, 0, 0);
}

typedef __attribute__((address_space(1))) const void glob_cv;
typedef __attribute__((address_space(3))) void lds_v;
__device__ __forceinline__ void gload16(const void* g, void* l) {
  __builtin_amdgcn_global_load_lds((glob_cv*)g, (lds_v*)l, 16, 0, 0);
}

// 256-thread 64x64 bf16 tile stage with XOR group swizzle on the GLOBAL
// source (LDS dest linear, m173 pattern). 2 gload_lds per thread.
__device__ __forceinline__ void stage32(const unsigned short* __restrict__ g0,
                                        int stride, unsigned short* lds0, int tid) {
  #pragma unroll
  for (int it = 0; it < 2; ++it) {
    const int e = it * 256 + tid;            // e in [0,512)
    const int row = e >> 3, pg = e & 7;
    const int gg = pg ^ (row & 7);
    gload16(g0 + (size_t)row * stride + gg * 8, lds0 + e * 8);
  }
}

// Decode block id -> (ti: 64-row tile, sj: 128-col tile), causal.
// Row-pair p contributes 2(p+1) blocks; cumulative before p is p(p+1).
__device__ __forceinline__ void tri2_decode(int b, int& ti, int& sj) {
  int p = (int)((sqrtf(4.0f * (float)b + 1.0f) - 1.0f) * 0.5f);
  while ((p + 1) * (p + 2) <= b) ++p;
  while (p * (p + 1) > b) --p;
  const int r = b - p * (p + 1);
  if (r >= p + 1) { ti = 2 * p + 1; sj = r - (p + 1); }
  else            { ti = 2 * p;     sj = r; }
}

// ---------- prep2: invnorm + hb + hbTp + Sseg + ws zeroing (fused) ----------
__global__ __launch_bounds__(256, 2) void k_prep2(const float* __restrict__ x,
    float* __restrict__ invnorm, unsigned short* __restrict__ hb,
    unsigned short* __restrict__ hbTp, float* __restrict__ Sseg,
    float* __restrict__ zero3) {
  __shared__ unsigned short Ts[16 * PSTR];   // 28.8 KB
  const int b = (int)blockIdx.x;             // rows t0..t0+15 == segment b
  const int t0 = b * 16;
  const int tid = (int)threadIdx.x, wv = tid >> 6, lane = tid & 63;

  // zero dmaxu+gn2+dist2 (3T = 12288 words) from blocks 0..47
  if (b < 48) zero3[b * 256 + tid] = 0.f;

  // Each wave: 4 rows. Batch loads first (16 global loads in flight).
  float4 v[4][4];
  #pragma unroll
  for (int rr = 0; rr < 4; ++rr) {
    const int t = t0 + wv * 4 + rr;
    #pragma unroll
    for (int k = 0; k < 4; ++k) {
      const int c4 = lane + 64 * k;          // float4 index; 224 per row
      if (k < 3 || lane < 32)
        v[rr][k] = *(const float4*)(x + (size_t)t * D_ + c4 * 4);
    }
  }
  #pragma unroll
  for (int rr = 0; rr < 4; ++rr) {
    const int row = wv * 4 + rr;
    const int t = t0 + row;
    float s = 0.f;
    #pragma unroll
    for (int k = 0; k < 4; ++k)
      if (k < 3 || lane < 32)
        s += v[rr][k].x * v[rr][k].x + v[rr][k].y * v[rr][k].y +
             v[rr][k].z * v[rr][k].z + v[rr][k].w * v[rr][k].w;
    #pragma unroll
    for (int off = 32; off > 0; off >>= 1) s += __shfl_down(s, off, 64);
    const float iv = 1.0f / fmaxf(sqrtf(__shfl(s, 0, 64)), 1e-12f);
    if (lane == 0) invnorm[t] = iv;
    #pragma unroll
    for (int k = 0; k < 4; ++k) {
      const int c4 = lane + 64 * k;
      if (k < 3 || lane < 32) {
        const ushort4 o = make_ushort4(f2bf(v[rr][k].x * iv), f2bf(v[rr][k].y * iv),
                                       f2bf(v[rr][k].z * iv), f2bf(v[rr][k].w * iv));
        *(ushort4*)(hb + (size_t)t * D_ + c4 * 4) = o;
        *(ushort4*)(&Ts[row * PSTR + c4 * 4]) = o;
      }
    }
  }
  __syncthreads();

  // Sseg[b][c]: sum of the 16 rows in 4-row groups, left-assoc (sega order).
  for (int c = tid; c < D_; c += 256) {
    float segsum = 0.f;
    #pragma unroll
    for (int q = 0; q < 4; ++q) {
      float gs = 0.f;
      #pragma unroll
      for (int r = 0; r < 4; ++r)
        gs += bf2f(Ts[(q * 4 + r) * PSTR + c]);
      segsum += gs;
    }
    Sseg[(size_t)b * D_ + c] = segsum;
  }

  // Transpose: hbTp[d][32 + t0 + 0..15] for all 896 d. 3584 ushort4 stores.
  #pragma unroll 2
  for (int it = 0; it < 14; ++it) {
    const int e = it * 256 + tid;            // 0..3583
    const int d = e >> 2, q = e & 3;
    const ushort4 o = make_ushort4(Ts[(q * 4 + 0) * PSTR + d],
                                   Ts[(q * 4 + 1) * PSTR + d],
                                   Ts[(q * 4 + 2) * PSTR + d],
                                   Ts[(q * 4 + 3) * PSTR + d]);
    *(ushort4*)(hbTp + (size_t)d * TP + 32 + t0 + q * 4) = o;
  }
  if (b == 0) {   // zero the 32 leading pad cols for all d rows
    for (int e = tid; e < D_ * 8; e += 256) {
      const int d = e >> 3, cc = (e & 7) * 4;
      *(ushort4*)(hbTp + (size_t)d * TP + cc) = make_ushort4(0, 0, 0, 0);
    }
  }
}

// ---------- bandw (+segb in wave 3): sims -> weights + invL; column scan ----------
__global__ __launch_bounds__(256) void k_bandw(const unsigned short* __restrict__ hb,
    const float* __restrict__ Sseg, float* __restrict__ Eseg,
    unsigned short* __restrict__ wband, float* __restrict__ invLb) {
  const int b = (int)blockIdx.x;
  const int t0 = b * 16;
  const int tid = (int)threadIdx.x;
  const int wv = tid >> 6, lane = tid & 63;
  const int tcol = lane & 15, quad = lane >> 4;
  __shared__ float sims[16][52];
  if (wv < 3) {
    const int s_base = t0 - 32 + wv * 16;
    if (s_base + 15 >= 0) {
      const int srow = max(s_base + tcol, 0);   // clamped; guarded below
      f32x4 acc = {};
      const unsigned short* arow = hb + (size_t)srow * D_ + quad * 8;
      const unsigned short* brow = hb + (size_t)(t0 + tcol) * D_ + quad * 8;
      #pragma unroll 1
      for (int c4 = 0; c4 < 4; ++c4) {          // 7 load-pairs in flight per step
        u16x8 av[7], bv[7];
        #pragma unroll
        for (int i = 0; i < 7; ++i) {
          av[i] = ld16(arow + (c4 * 7 + i) * 32);
          bv[i] = ld16(brow + (c4 * 7 + i) * 32);
        }
        #pragma unroll
        for (int i = 0; i < 7; ++i) acc = mfma16(av[i], bv[i], acc);
      }
      #pragma unroll
      for (int r = 0; r < 4; ++r)       // C[m=s_local=quad*4+r][n=t_local=tcol]
        sims[tcol][wv * 16 + quad * 4 + r] = acc[r];
    }
  } else if (b < 224) {
    // wave 3 (idle in phase 1): the former k_segb, 4 columns sequentially.
    #pragma unroll 1
    for (int cc = 0; cc < 4; ++cc) {
      const int c = b * 4 + cc;                 // column 0..895
      float v0 = Sseg[(size_t)lane * D_ + c];
      float v1 = Sseg[(size_t)(64 + lane) * D_ + c];
      float v2 = Sseg[(size_t)(128 + lane) * D_ + c];
      float v3 = Sseg[(size_t)(192 + lane) * D_ + c];
      const float o0 = v0, o1 = v1, o2 = v2, o3 = v3;
      #pragma unroll
      for (int off = 1; off < 64; off <<= 1) {
        const float n0 = __shfl_up(v0, off, 64);
        const float n1 = __shfl_up(v1, off, 64);
        const float n2 = __shfl_up(v2, off, 64);
        const float n3 = __shfl_up(v3, off, 64);
        if (lane >= off) { v0 += n0; v1 += n1; v2 += n2; v3 += n3; }
      }
      const float tot0 = __shfl(v0, 63, 64);
      const float tot1 = __shfl(v1, 63, 64);
      const float tot2 = __shfl(v2, 63, 64);
      Eseg[(size_t)lane * D_ + c] = v0 - o0;              // exclusive
      Eseg[(size_t)(64 + lane) * D_ + c] = v1 - o1 + tot0;
      Eseg[(size_t)(128 + lane) * D_ + c] = v2 - o2 + (tot0 + tot1);
      Eseg[(size_t)(192 + lane) * D_ + c] = v3 - o3 + (tot0 + tot1 + tot2);
    }
  }
  __syncthreads();
  if (wv == 0) {
    u16x8 af0, af1;
    float lsum = 0.f;
    #pragma unroll
    for (int j = 0; j < 8; ++j) {
      {
        const int k = quad * 8 + j;                 // k in [0,32)
        const int dt = tcol + 32 - k;               // >= 1
        const int s = t0 - 32 + k;
        unsigned short wb = 0;
        if (dt < 32 && s >= 0)
          wb = f2bf(__expf(sims[tcol][k] * (__expf(-0.1f * (float)dt) * 0.033407657f)));
        af0[j] = wb;
        lsum += bf2f(wb);
      }
      {
        const int k = 32 + quad * 8 + j;            // k in [32,64)
        const int dt = tcol + 32 - k;               // <= 15
        unsigned short wb = 0;
        if (dt >= 0)                                // k <= tcol+32 <= 47
          wb = f2bf(__expf(sims[tcol][k] * (__expf(-0.1f * (float)dt) * 0.033407657f)));
        af1[j] = wb;
        lsum += bf2f(wb);
      }
    }
    lsum += __shfl_xor(lsum, 16, 64);
    lsum += __shfl_xor(lsum, 32, 64);
    st16(wband + (size_t)(t0 + tcol) * 64 + quad * 8, af0);
    st16(wband + (size_t)(t0 + tcol) * 64 + 32 + quad * 8, af1);
    if (lane < 16) {
      const int t = t0 + lane;
      invLb[t] = 1.0f / (lsum + ((t >= 32) ? (float)(t - 31) : 0.f));
    }
  }
}

// ---------- bandg: band GEMM + in-register prefix (P eliminated) ----------
__global__ __launch_bounds__(256) void k_bandg(const unsigned short* __restrict__ hbTp,
    const unsigned short* __restrict__ wband, const float* __restrict__ invLb,
    const float* __restrict__ Eseg, const float* __restrict__ x,
    const float* __restrict__ invnorm, unsigned short* __restrict__ gb,
    float* __restrict__ gn2, float* __restrict__ dist2) {
  const int t0 = (int)blockIdx.x * 16;
  const int by = (int)blockIdx.y;             // 8 d-groups of 7 tiles
  const int tid = (int)threadIdx.x;
  const int wv = tid >> 6, lane = tid & 63;
  const int tcol = lane & 15, quad = lane >> 4;
  const u16x8 af0 = ld16(wband + (size_t)(t0 + tcol) * 64 + quad * 8);
  const u16x8 af1 = ld16(wband + (size_t)(t0 + tcol) * 64 + 32 + quad * 8);
  const int sg = (t0 >> 4) - 2;               // segment of rows t0-32..t0-17
  float invLr[4], inrr[4];
  #pragma unroll
  for (int r = 0; r < 4; ++r) {
    const int tt = t0 + quad * 4 + r;
    invLr[r] = invLb[tt];
    inrr[r]  = invnorm[tt];
  }
  float sgl[4] = {0.f, 0.f, 0.f, 0.f}, sdl[4] = {0.f, 0.f, 0.f, 0.f};
  for (int i = wv; i < 7; i += 4) {
    const int d = (by * 7 + i) * 16 + tcol;
    const unsigned short* brow = hbTp + (size_t)d * TP + t0 + quad * 8;
    const u16x8 b0 = ld16(brow);          // k in [0,32): zeros where s<0
    const u16x8 b1 = ld16(brow + 32);     // k in [32,64): tail x w=0 harmless
    f32x4 C = {};
    C = mfma16(af0, b0, C);
    C = mfma16(af1, b1, C);
    // P(t0-32+j) recomputed in-register: Eseg[sg][d] + sequential bf16 adds
    // over hbTp[d][t0 .. t0+15] (rows t0-32..t0-17). Same f32 order as the
    // old k_segc -> bit-identical.
    float pr[4] = {0.f, 0.f, 0.f, 0.f};
    if (t0 >= 32) {
      const unsigned short* prow = hbTp + (size_t)d * TP + t0;
      const uint4 w0 = *(const uint4*)prow;
      const uint4 w1 = *(const uint4*)(prow + 8);
      const unsigned int wz[8] = {w0.x, w0.y, w0.z, w0.w, w1.x, w1.y, w1.z, w1.w};
      float run = Eseg[(size_t)sg * D_ + d];
      #pragma unroll
      for (int jj = 0; jj < 16; ++jj) {
        const unsigned int uu = wz[jj >> 1];
        const unsigned short hh =
            (jj & 1) ? (unsigned short)(uu >> 16) : (unsigned short)(uu & 0xffffu);
        run += bf2f(hh);
        if ((jj >> 2) == quad) pr[jj & 3] = run;
      }
    }
    #pragma unroll
    for (int r = 0; r < 4; ++r) {     // C[m=quad*4+r -> t][n=tcol -> d]
      const int tt = t0 + quad * 4 + r;
      float gacc = C[r];
      if (tt >= 32) gacc += pr[r];
      const float g = gacc * invLr[r];
      gb[(size_t)tt * D_ + d] = f2bf(g);
      const float e = x[(size_t)tt * D_ + d] * inrr[r] - g;
      sgl[r] += g * g;
      sdl[r] += e * e;
    }
  }
  #pragma unroll
  for (int r = 0; r < 4; ++r) {
    float sg2 = sgl[r], sd = sdl[r];
    sg2 += __shfl_xor(sg2, 1, 64); sg2 += __shfl_xor(sg2, 2, 64);
    sg2 += __shfl_xor(sg2, 4, 64); sg2 += __shfl_xor(sg2, 8, 64);
    sd += __shfl_xor(sd, 1, 64); sd += __shfl_xor(sd, 2, 64);
    sd += __shfl_xor(sd, 4, 64); sd += __shfl_xor(sd, 8, 64);
    if (tcol == 0) {
      atomicAdd(&gn2[t0 + quad * 4 + r], sg2);
      atomicAdd(&dist2[t0 + quad * 4 + r], sd);
    }
  }
}

// ---------- GEMM3: cross = g h^T, 64x128 causal tiles (1056 blocks); row-max ----------
// v10 config (best measured): 4 waves x (64 rows x 32 cols), per ks 6
// ds_read_b128 feed 8 MFMA; 24.3 KB LDS -> 6 blocks/CU.
__global__ __launch_bounds__(256, 5) void k_gemm3(const unsigned short* __restrict__ gb,
    const unsigned short* __restrict__ hb, const float* __restrict__ gn2,
    unsigned int* __restrict__ dmaxu) {
  // Bijective XCD swizzle: 1056 = 8*132.
  const int bswz = ((int)blockIdx.x & 7) * 132 + ((int)blockIdx.x >> 3);
  int ti, sj;
  tri2_decode(bswz, ti, sj);
  const int t0 = ti * 64, s0 = sj * 128;
  __shared__ unsigned short As[64 * 64];    // 8 KB  (t rows)
  __shared__ unsigned short Bs[128 * 64];   // 16 KB (s rows)
  __shared__ unsigned int dmx[64];          // per-block row-max merge
  const int tid = (int)threadIdx.x;
  const int lane = tid & 63, wv = tid >> 6;
  const int tcol = lane & 15, quad = lane >> 4;
  if (tid < 64) dmx[tid] = 0u;
  f32x4 acc[4][2] = {};

  for (int kc = 0; kc < 14; ++kc) {
    __syncthreads();   // prev chunk's reads done before overwrite (also fences dmx init)
    stage32(gb + (size_t)t0 * D_ + kc * 64, D_, As, tid);
    stage32(hb + (size_t)s0 * D_ + kc * 64, D_, Bs, tid);
    stage32(hb + (size_t)(s0 + 64) * D_ + kc * 64, D_, Bs + 64 * 64, tid);
    __syncthreads();   // staged data visible
    #pragma unroll
    for (int ks = 0; ks < 2; ++ks) {
      const int go = ((ks * 4 + quad) ^ (tcol & 7)) * 8;
      u16x8 bf[2], af[4];
      #pragma unroll
      for (int ni = 0; ni < 2; ++ni)
        bf[ni] = ld16(&Bs[(wv * 32 + ni * 16 + tcol) * 64 + go]);
      #pragma unroll
      for (int mi = 0; mi < 4; ++mi)
        af[mi] = ld16(&As[(mi * 16 + tcol) * 64 + go]);
      #pragma unroll
      for (int mi = 0; mi < 4; ++mi)
        #pragma unroll
        for (int ni = 0; ni < 2; ++ni)
          acc[mi][ni] = mfma16(af[mi], bf[ni], acc[mi][ni]);
    }
  }

  // epilogue: m2[t] = max over this wave's 32-col strip, merge in LDS, then global
  #pragma unroll
  for (int mi = 0; mi < 4; ++mi) {
    #pragma unroll
    for (int r = 0; r < 4; ++r) {
      const int t = t0 + mi * 16 + quad * 4 + r;
      const float gn = gn2[t];
      float m2 = 0.f;
      #pragma unroll
      for (int ni = 0; ni < 2; ++ni) {
        const int s = s0 + wv * 32 + ni * 16 + tcol;
        if (t >= s)
          m2 = fmaxf(m2, fmaxf(1.0f - 2.0f * acc[mi][ni][r] + gn, 1e-24f));
      }
      m2 = fmaxf(m2, __shfl_xor(m2, 1, 64));
      m2 = fmaxf(m2, __shfl_xor(m2, 2, 64));
      m2 = fmaxf(m2, __shfl_xor(m2, 4, 64));
      m2 = fmaxf(m2, __shfl_xor(m2, 8, 64));
      if (tcol == 0 && m2 > 0.f)
        atomicMax(&dmx[mi * 16 + quad * 4 + r], __float_as_uint(m2));
    }
  }
  __syncthreads();
  if (tid < 64) {
    const unsigned int v = dmx[tid];
    if (v) atomicMax(&dmaxu[t0 + tid], v);
  }
}

__global__ __launch_bounds__(256) void k_final(const float* __restrict__ m_t,
    const float* __restrict__ c_t, const float* __restrict__ d_t,
    const float* __restrict__ mu, const float* __restrict__ dist2,
    const unsigned int* __restrict__ dmaxu, float* __restrict__ out) {
  const int t = (int)blockIdx.x * 256 + (int)threadIdx.x;
  if (t >= T_) return;
  float ratio;
  if (t == 0) {
    ratio = 0.f;  // ref: dist~1e-12, dist_max<1e-6 -> 1.0 => ratio ~0
  } else {
    float dmax = sqrtf(__uint_as_float(dmaxu[t]));
    if (dmax < 1e-6f) dmax = 1.0f;
    ratio = sqrtf(fmaxf(dist2[t], 1e-24f)) / (dmax + 1e-8f);
  }
  const float stab = 1.0f - 0.3f * c_t[t] + 0.2f * d_t[t];
  const float xi = 1.0f - mu[0] * m_t[t];
  out[t] = fminf(fmaxf(ratio * stab * xi, 0.f), 1.f);
}

extern "C" void kernel_launch(void* const* d_in, const int* in_sizes, int n_in,
                              void* d_out, int out_size, void* d_ws, size_t ws_size,
                              hipStream_t stream) {
  const float* x   = (const float*)d_in[0];
  const float* m_t = (const float*)d_in[1];
  const float* c_t = (const float*)d_in[2];
  const float* d_t = (const float*)d_in[3];
  const float* mu  = (const float*)d_in[4];
  float* out = (float*)d_out;

  float* ws = (float*)d_ws;
  float* invnorm = ws;                                          // [T]
  unsigned int* dmaxu = (unsigned int*)(ws + (size_t)T_);       // [T]
  float* gn2     = ws + 2 * (size_t)T_;                         // [T]
  float* dist2   = ws + 3 * (size_t)T_;                         // [T]
  float* invLb   = ws + 4 * (size_t)T_;                         // [T]
  float* Sseg    = ws + 5 * (size_t)T_;                         // [256*D]
  float* Eseg    = Sseg + 256 * (size_t)D_;                     // [256*D]
  float* Pold    = Eseg + 256 * (size_t)D_;                     // (unused region)
  unsigned short* hb    = (unsigned short*)(Pold + (size_t)T_ * D_);  // [T*D]
  unsigned short* hbTp  = hb + (size_t)T_ * D_;                    // [D*(T+64)]
  unsigned short* gb    = hbTp + (size_t)D_ * TP;                  // [T*D]
  unsigned short* wband = gb + (size_t)T_ * D_;                    // [T*64]

  float* zero3 = ws + (size_t)T_;   // dmaxu+gn2+dist2, zeroed inside k_prep2

  k_prep2<<<T_ / 16, 256, 0, stream>>>(x, invnorm, hb, hbTp, Sseg, zero3);
  k_bandw<<<T_ / 16, 256, 0, stream>>>(hb, Sseg, Eseg, wband, invLb);
  k_bandg<<<dim3(T_ / 16, 8), 256, 0, stream>>>(hbTp, wband, invLb, Eseg, x, invnorm,
                                                gb, gn2, dist2);
  k_gemm3<<<1056, 256, 0, stream>>>(gb, hb, gn2, dmaxu);
  k_final<<<(T_ + 255) / 256, 256, 0, stream>>>(m_t, c_t, d_t, mu, dist2, dmaxu, out);
}